// Round 1
// baseline (579.700 us; speedup 1.0000x reference)
//
#include <hip/hip_runtime.h>

#define H 64
#define NOBJ 512
#define BATCH 128
#define SCP 516   // sc row pitch (pad 4, 16B-aligned rows)

// ---------------- Kernel 1: fused q/k/v projections ----------------
// x: [N,B,H] (row = n*B+b), W: [H,H] (k,h), bias: [H] -> y: [B,N,H]
// grid (1024, 3), block 256. 64 rows per block.
__global__ __launch_bounds__(256) void proj_kernel(
    const float* __restrict__ q, const float* __restrict__ k, const float* __restrict__ v,
    const float* __restrict__ Wq, const float* __restrict__ bq,
    const float* __restrict__ Wk, const float* __restrict__ bk,
    const float* __restrict__ Wv, const float* __restrict__ bv,
    float* __restrict__ qp, float* __restrict__ kp, float* __restrict__ vp)
{
    const float* x; const float* W; const float* bias; float* y;
    if (blockIdx.y == 0)      { x = q; W = Wq; bias = bq; y = qp; }
    else if (blockIdx.y == 1) { x = k; W = Wk; bias = bk; y = kp; }
    else                      { x = v; W = Wv; bias = bv; y = vp; }

    __shared__ float  xs[64][68];      // x tile, padded
    __shared__ float4 wv[16][64];      // wv[hc][kk] = W[kk][4hc..4hc+3]
    const int tid = threadIdx.x;
    const int r0  = blockIdx.x * 64;

    #pragma unroll
    for (int i = 0; i < 4; i++) {                 // stage x: 1024 float4
        int f4 = i * 256 + tid;
        int row = f4 >> 4, hc = f4 & 15;
        float4 t = ((const float4*)(x + (size_t)(r0 + row) * H))[hc];
        *(float4*)&xs[row][hc * 4] = t;
    }
    #pragma unroll
    for (int i = 0; i < 4; i++) {                 // stage W: 1024 float4
        int f4 = i * 256 + tid;
        int kk = f4 >> 4, hc = f4 & 15;
        wv[hc][kk] = ((const float4*)(W + kk * H))[hc];
    }
    __syncthreads();

    const int kk = tid & 63;        // output column (lane)
    const int rg = tid >> 6;        // row group: rows rg*16 .. rg*16+15
    float bval = bias[kk];
    float acc[16];
    #pragma unroll
    for (int r = 0; r < 16; r++) acc[r] = bval;

    #pragma unroll
    for (int hc = 0; hc < 16; hc++) {
        float4 w = wv[hc][kk];                         // conflict-free b128
        #pragma unroll
        for (int r = 0; r < 16; r++) {
            float4 x4 = *(const float4*)&xs[rg * 16 + r][hc * 4];  // broadcast
            acc[r] = fmaf(x4.x, w.x, acc[r]);
            acc[r] = fmaf(x4.y, w.y, acc[r]);
            acc[r] = fmaf(x4.z, w.z, acc[r]);
            acc[r] = fmaf(x4.w, w.w, acc[r]);
        }
    }
    #pragma unroll
    for (int r = 0; r < 16; r++) {
        int row = r0 + rg * 16 + r;          // row = n*B + b
        int n = row >> 7;                    // /128
        int b = row & 127;
        y[((size_t)b * NOBJ + n) * H + kk] = acc[r];   // coalesced over kk
    }
}

// ---------------- Kernel 2: fused attention ----------------
// grid (16, 128): x = n-tile (32 rows), y = b. block 256.
__global__ __launch_bounds__(256, 1) void attn_kernel(
    const float* __restrict__ qp, const float* __restrict__ kp,
    const float* __restrict__ vp, const float* __restrict__ mask,
    float* __restrict__ out, float* __restrict__ Aout)
{
    __shared__ float sc[32][SCP];   // exp(score)*mask strip, 66 KB
    __shared__ float qt[64][36];    // qt[h][n]
    __shared__ float kt[64][132];   // kt[h][m], m-tile = 128
    __shared__ float vt[64][68];    // vt[m][h], m-tile = 64
    __shared__ float rs[32];        // row sums -> inverse row sums

    const int tid = threadIdx.x;
    const int n0  = blockIdx.x * 32;
    const int b   = blockIdx.y;

    // phase 0: stage q tile transposed
    const float* qpb = qp + ((size_t)b * NOBJ + n0) * H;
    #pragma unroll
    for (int i = 0; i < 2; i++) {
        int f4 = i * 256 + tid;
        int n = f4 >> 4, hc = f4 & 15;
        float4 t = ((const float4*)(qpb + n * H))[hc];
        qt[hc * 4 + 0][n] = t.x; qt[hc * 4 + 1][n] = t.y;
        qt[hc * 4 + 2][n] = t.z; qt[hc * 4 + 3][n] = t.w;
    }
    if (tid < 32) rs[tid] = 0.0f;

    const int ntg = tid >> 5;   // 0..7 : rows n = 4*ntg + i
    const int mtg = tid & 31;   // 0..31: cols m = m0 + 4*mtg + j
    const float* kpb   = kp   + (size_t)b * NOBJ * H;
    const float* maskb = mask + (size_t)b * NOBJ * NOBJ;

    for (int mt = 0; mt < 4; mt++) {
        const int m0 = mt * 128;
        __syncthreads();
        #pragma unroll
        for (int i = 0; i < 8; i++) {          // stage k tile transposed
            int f4 = i * 256 + tid;
            int m = f4 >> 4, hc = f4 & 15;
            float4 t = ((const float4*)(kpb + (size_t)(m0 + m) * H))[hc];
            kt[hc * 4 + 0][m] = t.x; kt[hc * 4 + 1][m] = t.y;
            kt[hc * 4 + 2][m] = t.z; kt[hc * 4 + 3][m] = t.w;
        }
        __syncthreads();

        float acc2[4][4];
        #pragma unroll
        for (int i = 0; i < 4; i++)
            #pragma unroll
            for (int j = 0; j < 4; j++) acc2[i][j] = 0.0f;

        #pragma unroll 4
        for (int h = 0; h < 64; h++) {
            float4 q4 = *(const float4*)&qt[h][4 * ntg];
            float4 k4 = *(const float4*)&kt[h][4 * mtg];
            float qa[4] = {q4.x, q4.y, q4.z, q4.w};
            float ka[4] = {k4.x, k4.y, k4.z, k4.w};
            #pragma unroll
            for (int i = 0; i < 4; i++)
                #pragma unroll
                for (int j = 0; j < 4; j++)
                    acc2[i][j] = fmaf(qa[i], ka[j], acc2[i][j]);
        }

        // exp * mask fused here (mask load overlaps compute), partial row sums
        float rp[4];
        #pragma unroll
        for (int i = 0; i < 4; i++) {
            float4 msk = *(const float4*)(maskb + (size_t)(n0 + 4 * ntg + i) * NOBJ + m0 + 4 * mtg);
            float4 e;
            e.x = __expf(acc2[i][0] * 0.125f) * msk.x;
            e.y = __expf(acc2[i][1] * 0.125f) * msk.y;
            e.z = __expf(acc2[i][2] * 0.125f) * msk.z;
            e.w = __expf(acc2[i][3] * 0.125f) * msk.w;
            *(float4*)&sc[4 * ntg + i][m0 + 4 * mtg] = e;
            rp[i] = e.x + e.y + e.z + e.w;
        }
        #pragma unroll
        for (int i = 0; i < 4; i++) {
            rp[i] += __shfl_down(rp[i], 16, 32);
            rp[i] += __shfl_down(rp[i],  8, 32);
            rp[i] += __shfl_down(rp[i],  4, 32);
            rp[i] += __shfl_down(rp[i],  2, 32);
            rp[i] += __shfl_down(rp[i],  1, 32);
        }
        if (mtg == 0) {
            #pragma unroll
            for (int i = 0; i < 4; i++) rs[4 * ntg + i] += rp[i];  // single writer per row
        }
    }
    __syncthreads();
    if (tid < 32) { float s = rs[tid]; rs[tid] = 1.0f / (s == 0.0f ? 1.0f : s); }
    __syncthreads();

    // A write: A = sc * inv, coalesced float4
    {
        const int nn = tid >> 3, mq = tid & 7;
        const float inv = rs[nn];
        float* Arow = Aout + ((size_t)b * NOBJ + n0 + nn) * NOBJ;
        #pragma unroll
        for (int i = 0; i < 16; i++) {
            int m = (i * 8 + mq) * 4;
            float4 e = *(const float4*)&sc[nn][m];
            e.x *= inv; e.y *= inv; e.z *= inv; e.w *= inv;
            *(float4*)(Arow + m) = e;
        }
    }

    // A·V: out[n,b,h] = inv[n] * sum_m sc[n][m] * vp[b][m][h]
    const int htg = tid & 31;
    const int hh  = 2 * htg;
    float oa[4][2] = {{0,0},{0,0},{0,0},{0,0}};
    const float* vpb = vp + (size_t)b * NOBJ * H;
    for (int t = 0; t < 8; t++) {
        const int m0 = t * 64;
        __syncthreads();
        #pragma unroll
        for (int i = 0; i < 4; i++) {          // stage v tile (no transpose)
            int f4 = i * 256 + tid;
            int m = f4 >> 4, hc = f4 & 15;
            *(float4*)&vt[m][hc * 4] = ((const float4*)(vpb + (size_t)(m0 + m) * H))[hc];
        }
        __syncthreads();
        for (int mm = 0; mm < 64; mm += 4) {
            float sv[4][4];
            *(float4*)&sv[0][0] = *(const float4*)&sc[4 * ntg + 0][m0 + mm];
            *(float4*)&sv[1][0] = *(const float4*)&sc[4 * ntg + 1][m0 + mm];
            *(float4*)&sv[2][0] = *(const float4*)&sc[4 * ntg + 2][m0 + mm];
            *(float4*)&sv[3][0] = *(const float4*)&sc[4 * ntg + 3][m0 + mm];
            #pragma unroll
            for (int j = 0; j < 4; j++) {
                float2 v2 = *(const float2*)&vt[mm + j][hh];
                #pragma unroll
                for (int i = 0; i < 4; i++) {
                    oa[i][0] = fmaf(sv[i][j], v2.x, oa[i][0]);
                    oa[i][1] = fmaf(sv[i][j], v2.y, oa[i][1]);
                }
            }
        }
    }
    #pragma unroll
    for (int i = 0; i < 4; i++) {
        float inv = rs[4 * ntg + i];
        float2 o; o.x = oa[i][0] * inv; o.y = oa[i][1] * inv;
        *(float2*)(out + ((size_t)(n0 + 4 * ntg + i) * BATCH + b) * H + hh) = o;
    }
}

extern "C" void kernel_launch(void* const* d_in, const int* in_sizes, int n_in,
                              void* d_out, int out_size, void* d_ws, size_t ws_size,
                              hipStream_t stream)
{
    const float* q    = (const float*)d_in[0];
    const float* k    = (const float*)d_in[1];
    const float* v    = (const float*)d_in[2];
    const float* mask = (const float*)d_in[3];
    const float* Wq   = (const float*)d_in[4];
    const float* bq   = (const float*)d_in[5];
    const float* Wk   = (const float*)d_in[6];
    const float* bk   = (const float*)d_in[7];
    const float* Wv   = (const float*)d_in[8];
    const float* bv   = (const float*)d_in[9];

    float* out  = (float*)d_out;                                  // [N,B,H]
    float* Aout = (float*)d_out + (size_t)NOBJ * BATCH * H;       // [B,N,N]

    float* qp = (float*)d_ws;                                     // [B,N,H] each
    float* kp = qp + (size_t)BATCH * NOBJ * H;
    float* vp = kp + (size_t)BATCH * NOBJ * H;

    proj_kernel<<<dim3(1024, 3), 256, 0, stream>>>(q, k, v, Wq, bq, Wk, bk, Wv, bv, qp, kp, vp);
    attn_kernel<<<dim3(16, 128), 256, 0, stream>>>(qp, kp, vp, mask, out, Aout);
}

// Round 3
// 516.503 us; speedup vs baseline: 1.1224x; 1.1224x over previous
//
#include <hip/hip_runtime.h>

#define H 64
#define NOBJ 512
#define BATCH 128

// ---------------- Kernel 1: fused q/k/v projections (register-W, scalar-x) ----
// x: [N,B,H] (row = n*B+b), W: [H,H] (k,h layout), bias: [H] -> y: [B,N,H]
// grid (256, 3), block 256 = 4 waves; each wave does 64 rows. No LDS.
__global__ __launch_bounds__(256) void proj_kernel(
    const float* __restrict__ q, const float* __restrict__ k, const float* __restrict__ v,
    const float* __restrict__ Wq, const float* __restrict__ bq,
    const float* __restrict__ Wk, const float* __restrict__ bk,
    const float* __restrict__ Wv, const float* __restrict__ bv,
    float* __restrict__ qp, float* __restrict__ kp, float* __restrict__ vp)
{
    const float* x; const float* W; const float* bias; float* y;
    if (blockIdx.y == 0)      { x = q; W = Wq; bias = bq; y = qp; }
    else if (blockIdx.y == 1) { x = k; W = Wk; bias = bk; y = kp; }
    else                      { x = v; W = Wv; bias = bv; y = vp; }

    const int tid  = threadIdx.x;
    const int lane = tid & 63;
    const int wid  = __builtin_amdgcn_readfirstlane(tid >> 6);   // wave-uniform

    // y[..,lane] = sum_h x[h] * W[lane][h]  -> need ROW `lane` of W (contiguous)
    float w[64];
    {
        const float4* Wr = (const float4*)(W + (size_t)lane * 64);
        #pragma unroll
        for (int hc = 0; hc < 16; ++hc) {
            float4 t = Wr[hc];
            w[hc * 4 + 0] = t.x; w[hc * 4 + 1] = t.y;
            w[hc * 4 + 2] = t.z; w[hc * 4 + 3] = t.w;
        }
    }
    const float bval = bias[lane];

    const int r0 = blockIdx.x * 256 + wid * 64;
    for (int r = 0; r < 64; ++r) {
        const int row = r0 + r;                        // wave-uniform
        const float* __restrict__ xr = x + (size_t)row * H;  // uniform -> s_load
        float a0 = bval, a1 = 0.0f, a2 = 0.0f, a3 = 0.0f;
        #pragma unroll
        for (int h = 0; h < 64; h += 4) {
            a0 = fmaf(xr[h + 0], w[h + 0], a0);
            a1 = fmaf(xr[h + 1], w[h + 1], a1);
            a2 = fmaf(xr[h + 2], w[h + 2], a2);
            a3 = fmaf(xr[h + 3], w[h + 3], a3);
        }
        const int n = row >> 7, b = row & 127;
        y[((size_t)b * NOBJ + n) * H + lane] = (a0 + a1) + (a2 + a3);
    }
}

// ---------------- Kernel 2: fused attention ----------------
// grid (32, 128): x = n-tile (16 rows), y = b. block 256 = 4 waves.
// LDS ~70 KB -> 2 blocks/CU (8 waves/CU).
__global__ __launch_bounds__(256, 2) void attn_kernel(
    const float* __restrict__ qp, const float* __restrict__ kp,
    const float* __restrict__ vp, const float* __restrict__ mask,
    float* __restrict__ out, float* __restrict__ Aout)
{
    __shared__ float sc[16][516];        // exp(score)*mask strip, 33.0 KB (reused as red)
    __shared__ float ktvt[32 * 260];     // union: kt[32][260] / vt[64][68], 33.3 KB
    __shared__ float qt[64][20];         // qt[h][n], 5.1 KB
    __shared__ float rs[16];
    __shared__ float inv[16];

    float (*kt)[260] = (float(*)[260])ktvt;
    float (*vt)[68]  = (float(*)[68])ktvt;
    float* red = &sc[0][0];              // 4x1024 partials after sc is dead

    const int tid = threadIdx.x;
    const int n0  = blockIdx.x * 16;
    const int b   = blockIdx.y;

    const float* qpb   = qp   + ((size_t)b * NOBJ + n0) * H;
    const float* kpb   = kp   + (size_t)b * NOBJ * H;
    const float* vpb   = vp   + (size_t)b * NOBJ * H;
    const float* maskb = mask + (size_t)b * NOBJ * NOBJ;

    // stage qt[h][n] (16 rows x 64 h)
    {
        const int nn = tid >> 4, hc = tid & 15;
        float4 t = ((const float4*)(qpb + nn * H))[hc];
        qt[hc * 4 + 0][nn] = t.x; qt[hc * 4 + 1][nn] = t.y;
        qt[hc * 4 + 2][nn] = t.z; qt[hc * 4 + 3][nn] = t.w;
    }

    const int w   = tid >> 6;    // wave id = row group (rows 4w..4w+3)
    const int mtg = tid & 63;    // lane = m group (4 cols)
    float rp[4] = {0.0f, 0.0f, 0.0f, 0.0f};

    // ---- score phase: 2 m-tiles of 256, each with 2 h-chunks of 32 ----
    for (int mt = 0; mt < 2; ++mt) {
        const int m0 = mt * 256;
        // prefetch mask early (used after compute)
        float4 msk[4];
        #pragma unroll
        for (int i = 0; i < 4; ++i)
            msk[i] = *(const float4*)(maskb + (size_t)(n0 + 4 * w + i) * NOBJ + m0 + 4 * mtg);

        float acc[4][4] = {};
        for (int hcb = 0; hcb < 2; ++hcb) {
            const int h0 = hcb * 32;
            __syncthreads();
            #pragma unroll
            for (int i = 0; i < 8; ++i) {        // stage kt[32][260] transposed
                int f4 = i * 256 + tid;
                int m = f4 >> 3, hq = f4 & 7;
                float4 t = ((const float4*)(kpb + (size_t)(m0 + m) * H + h0))[hq];
                kt[hq * 4 + 0][m] = t.x; kt[hq * 4 + 1][m] = t.y;
                kt[hq * 4 + 2][m] = t.z; kt[hq * 4 + 3][m] = t.w;
            }
            __syncthreads();
            #pragma unroll 8
            for (int hl = 0; hl < 32; ++hl) {
                float4 q4 = *(const float4*)&qt[h0 + hl][4 * w];   // wave-broadcast
                float4 k4 = *(const float4*)&kt[hl][4 * mtg];      // stride-16B, conflict-free
                float qa[4] = {q4.x, q4.y, q4.z, q4.w};
                float ka[4] = {k4.x, k4.y, k4.z, k4.w};
                #pragma unroll
                for (int i = 0; i < 4; ++i)
                    #pragma unroll
                    for (int j = 0; j < 4; ++j)
                        acc[i][j] = fmaf(qa[i], ka[j], acc[i][j]);
            }
        }
        // exp * mask, write strip, row-sum partials
        #pragma unroll
        for (int i = 0; i < 4; ++i) {
            float4 e;
            e.x = __expf(acc[i][0] * 0.125f) * msk[i].x;
            e.y = __expf(acc[i][1] * 0.125f) * msk[i].y;
            e.z = __expf(acc[i][2] * 0.125f) * msk[i].z;
            e.w = __expf(acc[i][3] * 0.125f) * msk[i].w;
            *(float4*)&sc[4 * w + i][m0 + 4 * mtg] = e;
            rp[i] += (e.x + e.y) + (e.z + e.w);
        }
    }

    // full-wave reduction of row sums (one wave owns each row group)
    #pragma unroll
    for (int i = 0; i < 4; ++i) {
        rp[i] += __shfl_down(rp[i], 32);
        rp[i] += __shfl_down(rp[i], 16);
        rp[i] += __shfl_down(rp[i], 8);
        rp[i] += __shfl_down(rp[i], 4);
        rp[i] += __shfl_down(rp[i], 2);
        rp[i] += __shfl_down(rp[i], 1);
    }
    if (mtg == 0) {
        #pragma unroll
        for (int i = 0; i < 4; ++i) rs[4 * w + i] = rp[i];
    }
    __syncthreads();
    if (tid < 16) { float s = rs[tid]; inv[tid] = 1.0f / (s == 0.0f ? 1.0f : s); }
    __syncthreads();

    // ---- A write: A = sc * inv, coalesced float4 ----
    {
        const int row = tid >> 4, q16 = tid & 15;
        const float iv = inv[row];
        float* Arow = Aout + ((size_t)b * NOBJ + n0 + row) * NOBJ;
        #pragma unroll
        for (int i = 0; i < 8; ++i) {
            int m = i * 64 + q16 * 4;
            float4 e = *(const float4*)&sc[row][m];
            e.x *= iv; e.y *= iv; e.z *= iv; e.w *= iv;
            *(float4*)(Arow + m) = e;
        }
    }

    // ---- AV phase: out[n,h] = inv[n] * sum_m sc[n][m] * vt[m][h] ----
    // thread = (msl: wave, r4: 4 rows, htg: 4 h); 4-way m-split + reduction
    const int msl = __builtin_amdgcn_readfirstlane(tid >> 6);
    const int r4  = (tid >> 4) & 3;
    const int htg = tid & 15;
    float oacc[4][4] = {};

    for (int c = 0; c < 8; ++c) {
        __syncthreads();
        #pragma unroll
        for (int i = 0; i < 4; ++i) {            // stage vt[64][68]
            int f4 = i * 256 + tid;
            int m = f4 >> 4, hc = f4 & 15;
            float4 t = ((const float4*)(vpb + (size_t)(c * 64 + m) * H))[hc];
            *(float4*)&vt[m][hc * 4] = t;
        }
        __syncthreads();
        const int mb = msl * 16;
        #pragma unroll
        for (int j4 = 0; j4 < 4; ++j4) {
            const int ml = mb + j4 * 4;          // local m in chunk
            const int mg = c * 64 + ml;          // global m
            float sa[4][4], va[4][4];
            *(float4*)&sa[0][0] = *(const float4*)&sc[4 * r4 + 0][mg];
            *(float4*)&sa[1][0] = *(const float4*)&sc[4 * r4 + 1][mg];
            *(float4*)&sa[2][0] = *(const float4*)&sc[4 * r4 + 2][mg];
            *(float4*)&sa[3][0] = *(const float4*)&sc[4 * r4 + 3][mg];
            *(float4*)&va[0][0] = *(const float4*)&vt[ml + 0][4 * htg];
            *(float4*)&va[1][0] = *(const float4*)&vt[ml + 1][4 * htg];
            *(float4*)&va[2][0] = *(const float4*)&vt[ml + 2][4 * htg];
            *(float4*)&va[3][0] = *(const float4*)&vt[ml + 3][4 * htg];
            #pragma unroll
            for (int i = 0; i < 4; ++i)
                #pragma unroll
                for (int t = 0; t < 4; ++t)
                    #pragma unroll
                    for (int j = 0; j < 4; ++j)
                        oacc[i][j] = fmaf(sa[i][t], va[t][j], oacc[i][j]);
        }
    }

    __syncthreads();      // all sc reads done; reuse as reduction buffer
    #pragma unroll
    for (int i = 0; i < 4; ++i) {
        float4 o; o.x = oacc[i][0]; o.y = oacc[i][1]; o.z = oacc[i][2]; o.w = oacc[i][3];
        *(float4*)&red[msl * 1024 + (4 * r4 + i) * 64 + 4 * htg] = o;
    }
    __syncthreads();
    {
        const int nn = tid >> 4, h4 = (tid & 15) * 4;
        const int idx = nn * 64 + h4;
        float4 p0 = *(const float4*)&red[idx];
        float4 p1 = *(const float4*)&red[1024 + idx];
        float4 p2 = *(const float4*)&red[2048 + idx];
        float4 p3 = *(const float4*)&red[3072 + idx];
        const float iv = inv[nn];
        float4 o;
        o.x = ((p0.x + p1.x) + (p2.x + p3.x)) * iv;
        o.y = ((p0.y + p1.y) + (p2.y + p3.y)) * iv;
        o.z = ((p0.z + p1.z) + (p2.z + p3.z)) * iv;
        o.w = ((p0.w + p1.w) + (p2.w + p3.w)) * iv;
        *(float4*)(out + ((size_t)(n0 + nn) * BATCH + b) * H + h4) = o;
    }
}

extern "C" void kernel_launch(void* const* d_in, const int* in_sizes, int n_in,
                              void* d_out, int out_size, void* d_ws, size_t ws_size,
                              hipStream_t stream)
{
    const float* q    = (const float*)d_in[0];
    const float* k    = (const float*)d_in[1];
    const float* v    = (const float*)d_in[2];
    const float* mask = (const float*)d_in[3];
    const float* Wq   = (const float*)d_in[4];
    const float* bq   = (const float*)d_in[5];
    const float* Wk   = (const float*)d_in[6];
    const float* bk   = (const float*)d_in[7];
    const float* Wv   = (const float*)d_in[8];
    const float* bv   = (const float*)d_in[9];

    float* out  = (float*)d_out;                                  // [N,B,H]
    float* Aout = (float*)d_out + (size_t)NOBJ * BATCH * H;       // [B,N,N]

    float* qp = (float*)d_ws;                                     // [B,N,H] each
    float* kp = qp + (size_t)BATCH * NOBJ * H;
    float* vp = kp + (size_t)BATCH * NOBJ * H;

    proj_kernel<<<dim3(256, 3), 256, 0, stream>>>(q, k, v, Wq, bq, Wk, bk, Wv, bv, qp, kp, vp);
    attn_kernel<<<dim3(32, 128), 256, 0, stream>>>(qp, kp, vp, mask, out, Aout);
}